// Round 6
// baseline (175.306 us; speedup 1.0000x reference)
//
#include <hip/hip_runtime.h>
#include <math.h>

#define T_SEQ   2048
#define DMODEL  512
#define NHEADS  8
#define DH      64
#define NEG_INF -1.0e9f

typedef __attribute__((ext_vector_type(8))) short short8;
typedef __attribute__((ext_vector_type(4))) float f32x4;
typedef unsigned int u32;
typedef unsigned short u16;

// cheap bf16 pack: round-half-up, error <= 2^-9 rel (same bound as RNE). No NaNs here.
__device__ __forceinline__ u16 f2bf(float f) {
    union { float f; u32 u; } w; w.f = f;
    return (u16)((w.u + 0x8000u) >> 16);
}

// async global->LDS, 16B per lane. LDS dest must be wave-uniform base + lane*16.
__device__ __forceinline__ void async_load16(const u16* g, u16* l) {
    __builtin_amdgcn_global_load_lds(
        (const __attribute__((address_space(1))) u32*)(const void*)g,
        (__attribute__((address_space(3))) u32*)(void*)l, 16, 0, 0);
}

// raw barrier: no compiler-inserted vmcnt(0) drain. sched_barrier + "memory"
// clobber pin ordering so LDS reads can't cross it.
__device__ __forceinline__ void barrier_raw() {
    __builtin_amdgcn_sched_barrier(0);
    asm volatile("s_barrier" ::: "memory");
    __builtin_amdgcn_sched_barrier(0);
}

// ---------------------------------------------------------------------------
// fused fp32->bf16 casts (x + 4 weights) + span-loss scalar. 5120 blocks.
// ---------------------------------------------------------------------------
__global__ void cast_all(const float* __restrict__ x,  const float* __restrict__ wq,
                         const float* __restrict__ wk, const float* __restrict__ wv,
                         const float* __restrict__ wo, const float* __restrict__ sp,
                         u16* __restrict__ xb,  u16* __restrict__ wqb,
                         u16* __restrict__ wkb, u16* __restrict__ wvb,
                         u16* __restrict__ wob, float* __restrict__ loss_out)
{
    const int bid = blockIdx.x;
    const float* src; u16* dst; int i;
    if (bid < 4096) { src = x; dst = xb; i = bid * 256 + threadIdx.x; }
    else {
        const int wsel = (bid - 4096) >> 8;
        src = (wsel == 0) ? wq : (wsel == 1) ? wk : (wsel == 2) ? wv : wo;
        dst = (wsel == 0) ? wqb : (wsel == 1) ? wkb : (wsel == 2) ? wvb : wob;
        i = ((bid - 4096) & 255) * 256 + threadIdx.x;
    }
    float4 v = ((const float4*)src)[i];
    ushort4 o;
    o.x = f2bf(v.x); o.y = f2bf(v.y); o.z = f2bf(v.z); o.w = f2bf(v.w);
    ((ushort4*)dst)[i] = o;
    if (bid == 5119 && threadIdx.x == 0) {
        float s = 0.0f;
        for (int h = 0; h < NHEADS; ++h)
            s += fminf(fmaxf(sp[h], 0.0f), 1.0f);
        loss_out[0] = 2e-4f * (s * 0.125f);
    }
}

// ---------------------------------------------------------------------------
// bf16 MFMA GEMM: C[m][n] = sum_k A[m][k]*W[n][k]  (A @ W^T)
// scatter=1: bf16 -> (B,H,T,DH) via LDS-coalesced epilogue; 0: fp32 row-major.
// ---------------------------------------------------------------------------
__global__ __launch_bounds__(256)
void gemm_bf16(const u16* __restrict__ A,
               const u16* __restrict__ W0, const u16* __restrict__ W1,
               const u16* __restrict__ W2,
               u16* __restrict__ Cb0, u16* __restrict__ Cb1,
               u16* __restrict__ Cb2,
               float* __restrict__ Cf, int scatter)
{
    constexpr int K = 512, BK = 64;
    const u16* W  = (blockIdx.z == 0) ? W0 : (blockIdx.z == 1) ? W1 : W2;
    u16*       Cb = (blockIdx.z == 0) ? Cb0 : (blockIdx.z == 1) ? Cb1 : Cb2;

    __shared__ __align__(16) u16 smem[16384];   // 32 KB: As|Bs, reused by epilogue
    u16* As = smem;
    u16* Bs = smem + 8192;

    const int t    = threadIdx.x;
    const int lane = t & 63;
    const int wave = t >> 6;
    const int wm   = wave >> 1, wn = wave & 1;
    const int m0   = blockIdx.x * 128, n0 = blockIdx.y * 128;

    const int srow = t >> 3;
    const int kb   = (t & 7) ^ (srow & 7);
    const u16* gA = A + (size_t)(m0 + srow) * K + kb * 8;
    const u16* gW = W + (size_t)(n0 + srow) * K + kb * 8;

    const int rA = wm * 64 + (lane & 15);
    const int rB = wn * 64 + (lane & 15);
    const int kq = lane >> 4;
    const int offA0 = rA * BK + ((kq      ^ (rA & 7)) * 8);
    const int offA1 = rA * BK + (((4 + kq) ^ (rA & 7)) * 8);
    const int offB0 = rB * BK + ((kq      ^ (rB & 7)) * 8);
    const int offB1 = rB * BK + (((4 + kq) ^ (rB & 7)) * 8);

    f32x4 acc[4][4];
#pragma unroll
    for (int it = 0; it < 4; ++it)
#pragma unroll
        for (int jt = 0; jt < 4; ++jt) acc[it][jt] = (f32x4)0.0f;

    for (int k0 = 0; k0 < K; k0 += BK) {
        __syncthreads();
#pragma unroll
        for (int i = 0; i < 4; ++i) {
            async_load16(gA + k0 + i * (32 * K), As + t * 8 + i * 2048);
            async_load16(gW + k0 + i * (32 * K), Bs + t * 8 + i * 2048);
        }
        __syncthreads();

        short8 af[4][2], bfr[4][2];
#pragma unroll
        for (int it = 0; it < 4; ++it) {
            af[it][0]  = *(const short8*)(As + offA0 + it * 16 * BK);
            af[it][1]  = *(const short8*)(As + offA1 + it * 16 * BK);
            bfr[it][0] = *(const short8*)(Bs + offB0 + it * 16 * BK);
            bfr[it][1] = *(const short8*)(Bs + offB1 + it * 16 * BK);
        }
#pragma unroll
        for (int it = 0; it < 4; ++it)
#pragma unroll
            for (int jt = 0; jt < 4; ++jt) {
                acc[it][jt] = __builtin_amdgcn_mfma_f32_16x16x32_bf16(
                    af[it][0], bfr[jt][0], acc[it][jt], 0, 0, 0);
                acc[it][jt] = __builtin_amdgcn_mfma_f32_16x16x32_bf16(
                    af[it][1], bfr[jt][1], acc[it][jt], 0, 0, 0);
            }
    }

    const int r0 = (lane >> 4) * 4;
    const int cl = lane & 15;

    if (scatter) {
        // two rounds; each stages a 64-row x 128-col bf16 slice (pitch 136) in LDS,
        // then stores coalesced uint4 to (B,H,T,DH).
        constexpr int P = 136;
#pragma unroll
        for (int rnd = 0; rnd < 2; ++rnd) {
            __syncthreads();   // prior use of smem done
#pragma unroll
            for (int s = 0; s < 2; ++s) {
                const int it = rnd * 2 + s;
                const int lrow = wm * 32 + s * 16 + r0;
#pragma unroll
                for (int jt = 0; jt < 4; ++jt) {
                    const int cc = wn * 64 + jt * 16 + cl;
#pragma unroll
                    for (int r = 0; r < 4; ++r)
                        smem[(lrow + r) * P + cc] = f2bf(acc[it][jt][r]);
                }
            }
            __syncthreads();
            const int lrow2 = t >> 2;
            const int h2    = (t >> 1) & 1;
            const int dhalf = t & 1;
            const int grow  = m0 + (lrow2 >> 5) * 64 + rnd * 32 + (lrow2 & 31);
            const int b     = grow >> 11, tt = grow & 2047;
            const int h     = (n0 >> 6) + h2;
            u16* dst = Cb + ((size_t)((b * NHEADS + h) * T_SEQ + tt)) * DH + dhalf * 32;
            const u16* srcl = smem + lrow2 * P + h2 * 64 + dhalf * 32;
#pragma unroll
            for (int i = 0; i < 4; ++i)
                ((uint4*)dst)[i] = *(const uint4*)(srcl + i * 8);
        }
    } else {
#pragma unroll
        for (int it = 0; it < 4; ++it) {
#pragma unroll
            for (int r = 0; r < 4; ++r) {
                const int row = m0 + wm * 64 + it * 16 + r0 + r;
#pragma unroll
                for (int jt = 0; jt < 4; ++jt) {
                    const int col = n0 + wn * 64 + jt * 16 + cl;
                    Cf[(size_t)row * DMODEL + col] = acc[it][jt][r];
                }
            }
        }
    }
}

// ---------------------------------------------------------------------------
// V (B,H,T,DH) -> Vt (B,H,DH,T), bf16, 64x64 LDS tiles.
// ---------------------------------------------------------------------------
__global__ __launch_bounds__(256)
void transpose_v(const u16* __restrict__ V, u16* __restrict__ Vt)
{
    __shared__ u16 tile[64][72];
    const int bh = blockIdx.y;
    const int j0 = blockIdx.x * 64;
    const u16* src = V + (size_t)bh * (T_SEQ * DH) + (size_t)j0 * DH;
    u16* dst = Vt + (size_t)bh * (T_SEQ * DH) + j0;
    const int t = threadIdx.x;
    const int jr = t >> 2, c0 = (t & 3) * 16;
    uint4 a = *(const uint4*)(src + (size_t)jr * DH + c0);
    uint4 b = *(const uint4*)(src + (size_t)jr * DH + c0 + 8);
    *(uint4*)&tile[jr][c0]     = a;
    *(uint4*)&tile[jr][c0 + 8] = b;
    __syncthreads();
    const int d = t >> 2, jc = (t & 3) * 16;
    union { uint4 v; u16 s[8]; } pa, pb;
#pragma unroll
    for (int i = 0; i < 8; ++i) pa.s[i] = tile[jc + i][d];
#pragma unroll
    for (int i = 0; i < 8; ++i) pb.s[i] = tile[jc + 8 + i][d];
    *(uint4*)(dst + (size_t)d * T_SEQ + jc)     = pa.v;
    *(uint4*)(dst + (size_t)d * T_SEQ + jc + 8) = pb.v;
}

// ---------------------------------------------------------------------------
// MFMA windowed flash attention v6 = round-5 + double-buffered K/V staging
// with counted vmcnt (T3/T4): prefetch tile t+1, wait vmcnt(8) (= only tile
// t's 8 loads done, prefetch stays in flight), raw barrier, compute.
// Removes the ~700cy/tile vmcnt(0) drain that __syncthreads imposed
// (round-5 counters: VALUBusy 43% == counted VALU work / wall; the rest
// was the drain). LDS 36.8 KB -> 4 blocks/CU; fewer but busier waves.
// Mapping unchanged (h = l>>8: every stride-256 resident set covers all 8
// heads -> per-CU work identical). Base-2 softmax.
// Q,K in (B,H,T,DH); Vt in (B,H,DH,T); out bf16 (B,T,DMODEL).
// ---------------------------------------------------------------------------
__device__ __forceinline__ void stage_kv(const u16* gK, const u16* gV,
                                         u16* Ksb, u16* Vsb, int tid, int jj)
{
#pragma unroll
    for (int i = 0; i < 4; ++i) {
        async_load16(gK + (size_t)(jj + i * 16) * DH,    Ksb + tid * 8 + i * 1024);
        async_load16(gV + jj + (size_t)(i * 16) * T_SEQ, Vsb + tid * 8 + i * 1024);
    }
}

__global__ __launch_bounds__(128)
void attn_mfma(const u16* __restrict__ Q, const u16* __restrict__ K,
               const u16* __restrict__ Vt, const float* __restrict__ span_params,
               u16* __restrict__ out)
{
    __shared__ __align__(16) u16 Ks[2][64 * 64];   // [j][dh], XOR-swizzled granules
    __shared__ __align__(16) u16 Vs[2][64 * 64];   // [dh][j], XOR-swizzled granules
    __shared__ __align__(16) u16 Ps[2][16 * 76];   // per-wave P [q][j], pitch 76

    const int tid  = threadIdx.x;
    const int lane = tid & 63;
    const int w    = tid >> 6;
    const int nl   = lane & 15;
    const int quad = lane >> 4;

    // balanced bijective mapping: l = h*256 + b*64 + qb
    const int l  = blockIdx.x;              // 0..2047
    const int h  = l >> 8;                  // 0..7
    const int b  = (l >> 6) & 3;
    const int qb = l & 63;
    const int bh = b * 8 + h;
    const int i0 = qb * 32;
    const int q0 = i0 + w * 16;

    const u16* Qh = Q  + (size_t)bh * (T_SEQ * DH);
    const u16* Kh = K  + (size_t)bh * (T_SEQ * DH);
    const u16* Vh = Vt + (size_t)bh * (DH * T_SEQ);

    float span = span_params[h];
    span = fminf(fmaxf(span, 0.0f), 1.0f);
    const float eff_span = span * 512.0f;
    const int wspan = (int)(eff_span + 1.0f) + 1;

    const float SCL = 0.125f * 1.44269504f;  // (1/sqrt(64)) * log2(e)

    // Q A-fragments in registers for the whole kernel
    short8 qf0 = *(const short8*)(Qh + (size_t)(q0 + nl) * DH + quad * 8);
    short8 qf1 = *(const short8*)(Qh + (size_t)(q0 + nl) * DH + 32 + quad * 8);

    // staging: 128 threads, 16 rows per issue, 4 issues per buffer per tensor
    const int srow = tid >> 3;                     // 0..15
    const int sg   = (tid & 7) ^ (srow & 7);
    const u16* gK = Kh + (size_t)srow * DH + sg * 8;
    const u16* gV = Vh + (size_t)srow * T_SEQ + sg * 8;

    f32x4 o[4];
    float m_r[4], l_r[4];
#pragma unroll
    for (int d = 0; d < 4; ++d) o[d] = (f32x4)0.0f;
#pragma unroll
    for (int r = 0; r < 4; ++r) { m_r[r] = -1.0e30f; l_r[r] = 0.0f; }

    int j_lo = i0 - wspan;
    if (j_lo < 0) j_lo = 0;
    j_lo &= ~63;
    const int nt = ((i0 + 31 - j_lo) >> 6) + 1;

    stage_kv(gK, gV, Ks[0], Vs[0], tid, j_lo);     // prologue: tile 0 -> buf 0

    for (int t = 0; t < nt; ++t) {
        const int j0  = j_lo + (t << 6);
        const int buf = t & 1;

        if (t + 1 < nt) {
            stage_kv(gK, gV, Ks[buf ^ 1], Vs[buf ^ 1], tid, j0 + 64);
            asm volatile("s_waitcnt vmcnt(8)" ::: "memory");  // tile t done; prefetch in flight
        } else {
            asm volatile("s_waitcnt vmcnt(0)" ::: "memory");
        }
        barrier_raw();                              // buf valid for both waves

        const u16* Kb = Ks[buf];
        const u16* Vb = Vs[buf];

        // ---- S = Q K^T per 16-wide key tile ----
        f32x4 s[4];
        bool any[4];
        __builtin_amdgcn_s_setprio(1);
#pragma unroll
        for (int n = 0; n < 4; ++n) {
            const int jn = j0 + n * 16;
            any[n] = (jn <= q0 + 15) &&
                     ((float)(q0 - jn - 15) < eff_span + 1.0f);   // R>0 exists
            s[n] = (f32x4)0.0f;
            if (any[n]) {
                const int row = n * 16 + nl;
                const u16* kp = Kb + row * 64;
                short8 b0 = *(const short8*)(kp + ((quad ^ (row & 7)) * 8));
                short8 b1 = *(const short8*)(kp + (((4 + quad) ^ (row & 7)) * 8));
                s[n] = __builtin_amdgcn_mfma_f32_16x16x32_bf16(qf0, b0, s[n], 0, 0, 0);
                s[n] = __builtin_amdgcn_mfma_f32_16x16x32_bf16(qf1, b1, s[n], 0, 0, 0);
            }
        }
        __builtin_amdgcn_s_setprio(0);

        // ---- mask + row max, 3-way tile classification (wave-uniform) ----
        float tmax[4] = {-1.0e30f, -1.0e30f, -1.0e30f, -1.0e30f};
#pragma unroll
        for (int n = 0; n < 4; ++n) {
            if (!any[n]) continue;
            const int jn = j0 + n * 16;
            const bool causal_b = (jn + 15 > q0);                           // some dist<0
            const bool span_b   = ((float)(q0 + 15 - jn) > eff_span - 3.0f); // some R<1
            if (!causal_b && !span_b) {
#pragma unroll
                for (int r = 0; r < 4; ++r) {
                    const float sv = s[n][r] * SCL;
                    s[n][r] = sv;
                    tmax[r] = fmaxf(tmax[r], sv);
                }
            } else if (!span_b) {
#pragma unroll
                for (int r = 0; r < 4; ++r) {
                    const int dist = (q0 + quad * 4 + r) - (jn + nl);
                    const float sv = (dist >= 0) ? s[n][r] * SCL : NEG_INF;
                    s[n][r] = sv;
                    tmax[r] = fmaxf(tmax[r], sv);
                }
            } else {
#pragma unroll
                for (int r = 0; r < 4; ++r) {
                    const int dist = (q0 + quad * 4 + r) - (jn + nl);
                    float sv = NEG_INF;
                    if (dist >= 0) {
                        float xv = eff_span - (float)dist;
                        float R  = fminf(fmaxf((xv + 1.0f) * 0.25f, 0.0f), 1.0f);
                        if (R > 0.0f)
                            sv = s[n][r] * SCL +
                                 ((R < 1.0f) ? __log2f(R + 1e-10f) : 0.0f);
                    }
                    s[n][r] = sv;
                    tmax[r] = fmaxf(tmax[r], sv);
                }
            }
        }

        // ---- online softmax state (base-2 domain) ----
        float alpha[4];
#pragma unroll
        for (int r = 0; r < 4; ++r) {
            float t2 = tmax[r];
            t2 = fmaxf(t2, __shfl_xor(t2, 1));
            t2 = fmaxf(t2, __shfl_xor(t2, 2));
            t2 = fmaxf(t2, __shfl_xor(t2, 4));
            t2 = fmaxf(t2, __shfl_xor(t2, 8));
            const float m_new = fmaxf(m_r[r], t2);
            alpha[r] = exp2f(m_r[r] - m_new);
            m_r[r] = m_new;
        }

        // ---- P = exp2(S - m) -> bf16 LDS (per-wave buffer) ----
        float psum[4] = {0.0f, 0.0f, 0.0f, 0.0f};
#pragma unroll
        for (int n = 0; n < 4; ++n) {
            if (any[n]) {
#pragma unroll
                for (int r = 0; r < 4; ++r) {
                    const float pv = exp2f(s[n][r] - m_r[r]);
                    psum[r] += pv;
                    Ps[w][(quad * 4 + r) * 76 + n * 16 + nl] = f2bf(pv);
                }
            } else {
#pragma unroll
                for (int r = 0; r < 4; ++r)
                    Ps[w][(quad * 4 + r) * 76 + n * 16 + nl] = 0;
            }
        }
#pragma unroll
        for (int r = 0; r < 4; ++r) {
            float ps = psum[r];
            ps += __shfl_xor(ps, 1);
            ps += __shfl_xor(ps, 2);
            ps += __shfl_xor(ps, 4);
            ps += __shfl_xor(ps, 8);
            l_r[r] = l_r[r] * alpha[r] + ps;
#pragma unroll
            for (int d = 0; d < 4; ++d) o[d][r] *= alpha[r];
        }

        // ---- O += P V ----
        const bool kf0 = any[0] | any[1];
        const bool kf1 = any[2] | any[3];
        const u16* pb = Ps[w] + nl * 76;
        short8 a0 = *(const short8*)(pb + quad * 8);
        short8 a1 = *(const short8*)(pb + 32 + quad * 8);
        __builtin_amdgcn_s_setprio(1);
#pragma unroll
        for (int d = 0; d < 4; ++d) {
            const int vrow = d * 16 + nl;
            const u16* vp = Vb + vrow * 64;
            if (kf0) {
                short8 vb0 = *(const short8*)(vp + ((quad ^ (vrow & 7)) * 8));
                o[d] = __builtin_amdgcn_mfma_f32_16x16x32_bf16(a0, vb0, o[d], 0, 0, 0);
            }
            if (kf1) {
                short8 vb1 = *(const short8*)(vp + (((4 + quad) ^ (vrow & 7)) * 8));
                o[d] = __builtin_amdgcn_mfma_f32_16x16x32_bf16(a1, vb1, o[d], 0, 0, 0);
            }
        }
        __builtin_amdgcn_s_setprio(0);

        barrier_raw();          // all waves done with buf before next prefetch overwrites
    }

    // ---- epilogue ----
#pragma unroll
    for (int r = 0; r < 4; ++r) {
        const int qg = q0 + quad * 4 + r;
        const float inv_l = 1.0f / l_r[r];
        u16* op = out + (size_t)(b * T_SEQ + qg) * DMODEL + h * 64;
#pragma unroll
        for (int d = 0; d < 4; ++d)
            op[d * 16 + nl] = f2bf(o[d][r] * inv_l);
    }
}

extern "C" void kernel_launch(void* const* d_in, const int* in_sizes, int n_in,
                              void* d_out, int out_size, void* d_ws, size_t ws_size,
                              hipStream_t stream)
{
    (void)in_sizes; (void)n_in; (void)out_size; (void)ws_size;
    const float* x  = (const float*)d_in[0];
    const float* wq = (const float*)d_in[1];
    const float* wk = (const float*)d_in[2];
    const float* wv = (const float*)d_in[3];
    const float* wo = (const float*)d_in[4];
    const float* sp = (const float*)d_in[5];
    float* out = (float*)d_out;

    const size_t elems = (size_t)4 * T_SEQ * DMODEL;  // 4,194,304
    u16* xb  = (u16*)d_ws;
    u16* Qb  = xb  + elems;
    u16* Kb  = Qb  + elems;
    u16* Vb  = Kb  + elems;
    u16* Vtb = Vb  + elems;
    u16* Ab  = Vtb + elems;
    u16* wqb = Ab  + elems;
    u16* wkb = wqb + 262144;
    u16* wvb = wkb + 262144;
    u16* wob = wvb + 262144;

    // casts + loss (one launch)
    cast_all<<<5120, 256, 0, stream>>>(x, wq, wk, wv, wo, sp,
                                       xb, wqb, wkb, wvb, wob, out + elems);
    // Q,K,V projections
    gemm_bf16<<<dim3(64, 4, 3), 256, 0, stream>>>(
        xb, wqb, wkb, wvb, Qb, Kb, Vb, nullptr, 1);
    // V -> V^T per head
    transpose_v<<<dim3(32, 32), 256, 0, stream>>>(Vb, Vtb);
    // LDS-staged dbuf MFMA windowed flash attention, head-balanced mapping
    attn_mfma<<<dim3(2048), 128, 0, stream>>>(Qb, Kb, Vtb, sp, Ab);
    // output projection (fp32 out)
    gemm_bf16<<<dim3(64, 4, 1), 256, 0, stream>>>(
        Ab, wob, wob, wob, nullptr, nullptr, nullptr, out, 0);
}

// Round 7
// 152.462 us; speedup vs baseline: 1.1498x; 1.1498x over previous
//
#include <hip/hip_runtime.h>
#include <math.h>

#define T_SEQ   2048
#define DMODEL  512
#define NHEADS  8
#define DH      64
#define NEG_INF -1.0e9f

typedef __attribute__((ext_vector_type(8))) short short8;
typedef __attribute__((ext_vector_type(4))) float f32x4;
typedef unsigned int u32;
typedef unsigned short u16;

// cheap bf16 pack: round-half-up, error <= 2^-9 rel (same bound as RNE). No NaNs here.
__device__ __forceinline__ u16 f2bf(float f) {
    union { float f; u32 u; } w; w.f = f;
    return (u16)((w.u + 0x8000u) >> 16);
}

// packed f32x2 -> bf16x2 (RNE), single instruction on gfx950
__device__ __forceinline__ u32 cvt_pk_bf16(float lo, float hi) {
    u32 r;
    asm("v_cvt_pk_bf16_f32 %0, %1, %2" : "=v"(r) : "v"(lo), "v"(hi));
    return r;
}

// async global->LDS, 16B per lane. LDS dest must be wave-uniform base + lane*16.
__device__ __forceinline__ void async_load16(const u16* g, u16* l) {
    __builtin_amdgcn_global_load_lds(
        (const __attribute__((address_space(1))) u32*)(const void*)g,
        (__attribute__((address_space(3))) u32*)(void*)l, 16, 0, 0);
}

// ---------------------------------------------------------------------------
// fused fp32->bf16 casts (x + 4 weights) + span-loss scalar. 5120 blocks.
// ---------------------------------------------------------------------------
__global__ void cast_all(const float* __restrict__ x,  const float* __restrict__ wq,
                         const float* __restrict__ wk, const float* __restrict__ wv,
                         const float* __restrict__ wo, const float* __restrict__ sp,
                         u16* __restrict__ xb,  u16* __restrict__ wqb,
                         u16* __restrict__ wkb, u16* __restrict__ wvb,
                         u16* __restrict__ wob, float* __restrict__ loss_out)
{
    const int bid = blockIdx.x;
    const float* src; u16* dst; int i;
    if (bid < 4096) { src = x; dst = xb; i = bid * 256 + threadIdx.x; }
    else {
        const int wsel = (bid - 4096) >> 8;
        src = (wsel == 0) ? wq : (wsel == 1) ? wk : (wsel == 2) ? wv : wo;
        dst = (wsel == 0) ? wqb : (wsel == 1) ? wkb : (wsel == 2) ? wvb : wob;
        i = ((bid - 4096) & 255) * 256 + threadIdx.x;
    }
    float4 v = ((const float4*)src)[i];
    ushort4 o;
    o.x = f2bf(v.x); o.y = f2bf(v.y); o.z = f2bf(v.z); o.w = f2bf(v.w);
    ((ushort4*)dst)[i] = o;
    if (bid == 5119 && threadIdx.x == 0) {
        float s = 0.0f;
        for (int h = 0; h < NHEADS; ++h)
            s += fminf(fmaxf(sp[h], 0.0f), 1.0f);
        loss_out[0] = 2e-4f * (s * 0.125f);
    }
}

// ---------------------------------------------------------------------------
// bf16 MFMA GEMM: C[m][n] = sum_k A[m][k]*W[n][k]  (A @ W^T)
// scatter=1: bf16 -> (B,H,T,DH) via LDS-coalesced epilogue; 0: fp32 row-major.
// ---------------------------------------------------------------------------
__global__ __launch_bounds__(256)
void gemm_bf16(const u16* __restrict__ A,
               const u16* __restrict__ W0, const u16* __restrict__ W1,
               const u16* __restrict__ W2,
               u16* __restrict__ Cb0, u16* __restrict__ Cb1,
               u16* __restrict__ Cb2,
               float* __restrict__ Cf, int scatter)
{
    constexpr int K = 512, BK = 64;
    const u16* W  = (blockIdx.z == 0) ? W0 : (blockIdx.z == 1) ? W1 : W2;
    u16*       Cb = (blockIdx.z == 0) ? Cb0 : (blockIdx.z == 1) ? Cb1 : Cb2;

    __shared__ __align__(16) u16 smem[16384];   // 32 KB: As|Bs, reused by epilogue
    u16* As = smem;
    u16* Bs = smem + 8192;

    const int t    = threadIdx.x;
    const int lane = t & 63;
    const int wave = t >> 6;
    const int wm   = wave >> 1, wn = wave & 1;
    const int m0   = blockIdx.x * 128, n0 = blockIdx.y * 128;

    const int srow = t >> 3;
    const int kb   = (t & 7) ^ (srow & 7);
    const u16* gA = A + (size_t)(m0 + srow) * K + kb * 8;
    const u16* gW = W + (size_t)(n0 + srow) * K + kb * 8;

    const int rA = wm * 64 + (lane & 15);
    const int rB = wn * 64 + (lane & 15);
    const int kq = lane >> 4;
    const int offA0 = rA * BK + ((kq      ^ (rA & 7)) * 8);
    const int offA1 = rA * BK + (((4 + kq) ^ (rA & 7)) * 8);
    const int offB0 = rB * BK + ((kq      ^ (rB & 7)) * 8);
    const int offB1 = rB * BK + (((4 + kq) ^ (rB & 7)) * 8);

    f32x4 acc[4][4];
#pragma unroll
    for (int it = 0; it < 4; ++it)
#pragma unroll
        for (int jt = 0; jt < 4; ++jt) acc[it][jt] = (f32x4)0.0f;

    for (int k0 = 0; k0 < K; k0 += BK) {
        __syncthreads();
#pragma unroll
        for (int i = 0; i < 4; ++i) {
            async_load16(gA + k0 + i * (32 * K), As + t * 8 + i * 2048);
            async_load16(gW + k0 + i * (32 * K), Bs + t * 8 + i * 2048);
        }
        __syncthreads();

        short8 af[4][2], bfr[4][2];
#pragma unroll
        for (int it = 0; it < 4; ++it) {
            af[it][0]  = *(const short8*)(As + offA0 + it * 16 * BK);
            af[it][1]  = *(const short8*)(As + offA1 + it * 16 * BK);
            bfr[it][0] = *(const short8*)(Bs + offB0 + it * 16 * BK);
            bfr[it][1] = *(const short8*)(Bs + offB1 + it * 16 * BK);
        }
#pragma unroll
        for (int it = 0; it < 4; ++it)
#pragma unroll
            for (int jt = 0; jt < 4; ++jt) {
                acc[it][jt] = __builtin_amdgcn_mfma_f32_16x16x32_bf16(
                    af[it][0], bfr[jt][0], acc[it][jt], 0, 0, 0);
                acc[it][jt] = __builtin_amdgcn_mfma_f32_16x16x32_bf16(
                    af[it][1], bfr[jt][1], acc[it][jt], 0, 0, 0);
            }
    }

    const int r0 = (lane >> 4) * 4;
    const int cl = lane & 15;

    if (scatter) {
        // two rounds; each stages a 64-row x 128-col bf16 slice (pitch 136) in LDS,
        // then stores coalesced uint4 to (B,H,T,DH).
        constexpr int P = 136;
#pragma unroll
        for (int rnd = 0; rnd < 2; ++rnd) {
            __syncthreads();   // prior use of smem done
#pragma unroll
            for (int s = 0; s < 2; ++s) {
                const int it = rnd * 2 + s;
                const int lrow = wm * 32 + s * 16 + r0;
#pragma unroll
                for (int jt = 0; jt < 4; ++jt) {
                    const int cc = wn * 64 + jt * 16 + cl;
#pragma unroll
                    for (int r = 0; r < 4; ++r)
                        smem[(lrow + r) * P + cc] = f2bf(acc[it][jt][r]);
                }
            }
            __syncthreads();
            const int lrow2 = t >> 2;
            const int h2    = (t >> 1) & 1;
            const int dhalf = t & 1;
            const int grow  = m0 + (lrow2 >> 5) * 64 + rnd * 32 + (lrow2 & 31);
            const int b     = grow >> 11, tt = grow & 2047;
            const int h     = (n0 >> 6) + h2;
            u16* dst = Cb + ((size_t)((b * NHEADS + h) * T_SEQ + tt)) * DH + dhalf * 32;
            const u16* srcl = smem + lrow2 * P + h2 * 64 + dhalf * 32;
#pragma unroll
            for (int i = 0; i < 4; ++i)
                ((uint4*)dst)[i] = *(const uint4*)(srcl + i * 8);
        }
    } else {
#pragma unroll
        for (int it = 0; it < 4; ++it) {
#pragma unroll
            for (int r = 0; r < 4; ++r) {
                const int row = m0 + wm * 64 + it * 16 + r0 + r;
#pragma unroll
                for (int jt = 0; jt < 4; ++jt) {
                    const int col = n0 + wn * 64 + jt * 16 + cl;
                    Cf[(size_t)row * DMODEL + col] = acc[it][jt][r];
                }
            }
        }
    }
}

// ---------------------------------------------------------------------------
// V (B,H,T,DH) -> Vt (B,H,DH,T), bf16, 64x64 LDS tiles.
// ---------------------------------------------------------------------------
__global__ __launch_bounds__(256)
void transpose_v(const u16* __restrict__ V, u16* __restrict__ Vt)
{
    __shared__ u16 tile[64][72];
    const int bh = blockIdx.y;
    const int j0 = blockIdx.x * 64;
    const u16* src = V + (size_t)bh * (T_SEQ * DH) + (size_t)j0 * DH;
    u16* dst = Vt + (size_t)bh * (T_SEQ * DH) + j0;
    const int t = threadIdx.x;
    const int jr = t >> 2, c0 = (t & 3) * 16;
    uint4 a = *(const uint4*)(src + (size_t)jr * DH + c0);
    uint4 b = *(const uint4*)(src + (size_t)jr * DH + c0 + 8);
    *(uint4*)&tile[jr][c0]     = a;
    *(uint4*)&tile[jr][c0 + 8] = b;
    __syncthreads();
    const int d = t >> 2, jc = (t & 3) * 16;
    union { uint4 v; u16 s[8]; } pa, pb;
#pragma unroll
    for (int i = 0; i < 8; ++i) pa.s[i] = tile[jc + i][d];
#pragma unroll
    for (int i = 0; i < 8; ++i) pb.s[i] = tile[jc + 8 + i][d];
    *(uint4*)(dst + (size_t)d * T_SEQ + jc)     = pa.v;
    *(uint4*)(dst + (size_t)d * T_SEQ + jc + 8) = pb.v;
}

// ---------------------------------------------------------------------------
// MFMA windowed flash attention v7 = round-5 skeleton + swapped-operand MFMA.
// mfma(K,Q) computes S^T: lane owns one q-row (q = lane&15) -> m/l/alpha/psum
// are per-lane SCALARS (2 shuffles per reduce instead of 16); mfma(V,P)
// computes O with q = lane&15 -> alpha rescale is a scalar broadcast, no
// redistribution. A/B frag layouts are identical per-lane, so the existing
// K/V LDS reads and Q register frags are reused unchanged. P round-trip:
// 8 cvt_pk + 4 ds_write_b64 + 2 ds_read_b128 (XOR-swizzled, conflict-free
// writes) vs old 16 ds_write_b16 + 32 pack ops + 16 shuffles.
// Ps 4.0 KB -> block LDS 20,480 B -> 8 blocks/CU (was 7).
// Staging/sync/mapping identical to round 5 (best measured: 44.4 us).
// Q,K in (B,H,T,DH); Vt in (B,H,DH,T); out bf16 (B,T,DMODEL).
// ---------------------------------------------------------------------------
__global__ __launch_bounds__(128)
void attn_mfma(const u16* __restrict__ Q, const u16* __restrict__ K,
               const u16* __restrict__ Vt, const float* __restrict__ span_params,
               u16* __restrict__ out)
{
    __shared__ __align__(16) u16 Ks[64 * 64];      // [j][dh], XOR-swizzled granules
    __shared__ __align__(16) u16 Vs[64 * 64];      // [dh][j], XOR-swizzled granules
    __shared__ __align__(16) u16 Ps[2][1024];      // per-wave P [q=16][j=64], row 128B

    const int tid  = threadIdx.x;
    const int lane = tid & 63;
    const int w    = tid >> 6;
    const int nl   = lane & 15;
    const int quad = lane >> 4;
    const int swz  = (nl & 7) << 3;                // u16-unit XOR (bytes: (nl&7)<<4)

    // balanced bijective mapping: l = h*256 + b*64 + qb
    const int l  = blockIdx.x;              // 0..2047
    const int h  = l >> 8;                  // 0..7
    const int b  = (l >> 6) & 3;
    const int qb = l & 63;
    const int bh = b * 8 + h;
    const int i0 = qb * 32;
    const int q0 = i0 + w * 16;

    const u16* Qh = Q  + (size_t)bh * (T_SEQ * DH);
    const u16* Kh = K  + (size_t)bh * (T_SEQ * DH);
    const u16* Vh = Vt + (size_t)bh * (DH * T_SEQ);

    float span = span_params[h];
    span = fminf(fmaxf(span, 0.0f), 1.0f);
    const float eff_span = span * 512.0f;
    const int wspan = (int)(eff_span + 1.0f) + 1;

    const float SCL = 0.125f * 1.44269504f;  // (1/sqrt(64)) * log2(e)

    // Q fragments (used as MFMA B-operand; same per-lane layout as A)
    short8 qf0 = *(const short8*)(Qh + (size_t)(q0 + nl) * DH + quad * 8);
    short8 qf1 = *(const short8*)(Qh + (size_t)(q0 + nl) * DH + 32 + quad * 8);

    // staging: 128 threads, 16 rows per issue, 4 issues per buffer
    const int srow = tid >> 3;                     // 0..15
    const int sg   = (tid & 7) ^ (srow & 7);
    const u16* gK = Kh + (size_t)srow * DH + sg * 8;
    const u16* gV = Vh + (size_t)srow * T_SEQ + sg * 8;

    f32x4 o[4];                 // O[q=nl][dcol = d*16 + quad*4 + r]
    float m_r = -1.0e30f, l_r = 0.0f;
#pragma unroll
    for (int d = 0; d < 4; ++d) o[d] = (f32x4)0.0f;

    int j_lo = i0 - wspan;
    if (j_lo < 0) j_lo = 0;
    j_lo &= ~63;

    u16* Psw = Ps[w];

    for (int j0 = j_lo; j0 <= i0 + 31; j0 += 64) {
        __syncthreads();
#pragma unroll
        for (int i = 0; i < 4; ++i) {
            async_load16(gK + (size_t)(j0 + i * 16) * DH, Ks + tid * 8 + i * 1024);
            async_load16(gV + j0 + (size_t)(i * 16) * T_SEQ, Vs + tid * 8 + i * 1024);
        }
        __syncthreads();

        // ---- S^T = K Q^T per 16-wide key tile: lane holds S[q=nl][j=quad*4+r]
        f32x4 s[4];
        bool any[4];
        __builtin_amdgcn_s_setprio(1);
#pragma unroll
        for (int n = 0; n < 4; ++n) {
            const int jn = j0 + n * 16;
            any[n] = (jn <= q0 + 15) &&
                     ((float)(q0 - jn - 15) < eff_span + 1.0f);   // R>0 exists
            s[n] = (f32x4)0.0f;
            if (any[n]) {
                const int row = n * 16 + nl;
                const u16* kp = Ks + row * 64;
                short8 b0 = *(const short8*)(kp + ((quad ^ (row & 7)) * 8));
                short8 b1 = *(const short8*)(kp + (((4 + quad) ^ (row & 7)) * 8));
                s[n] = __builtin_amdgcn_mfma_f32_16x16x32_bf16(b0, qf0, s[n], 0, 0, 0);
                s[n] = __builtin_amdgcn_mfma_f32_16x16x32_bf16(b1, qf1, s[n], 0, 0, 0);
            }
        }
        __builtin_amdgcn_s_setprio(0);

        // ---- mask + row max (per-lane scalar), 3-way tile classification ----
        const int qg = q0 + nl;
        float tmax = -1.0e30f;
#pragma unroll
        for (int n = 0; n < 4; ++n) {
            if (!any[n]) continue;
            const int jn = j0 + n * 16;
            const int jb = jn + quad * 4;
            const bool causal_b = (jn + 15 > q0);                           // some dist<0
            const bool span_b   = ((float)(q0 + 15 - jn) > eff_span - 3.0f); // some R<1
            if (!causal_b && !span_b) {
#pragma unroll
                for (int r = 0; r < 4; ++r) {
                    const float sv = s[n][r] * SCL;
                    s[n][r] = sv;
                    tmax = fmaxf(tmax, sv);
                }
            } else if (!span_b) {
#pragma unroll
                for (int r = 0; r < 4; ++r) {
                    const int dist = qg - (jb + r);
                    const float sv = (dist >= 0) ? s[n][r] * SCL : NEG_INF;
                    s[n][r] = sv;
                    tmax = fmaxf(tmax, sv);
                }
            } else {
#pragma unroll
                for (int r = 0; r < 4; ++r) {
                    const int dist = qg - (jb + r);
                    float sv = NEG_INF;
                    if (dist >= 0) {
                        float xv = eff_span - (float)dist;
                        float R  = fminf(fmaxf((xv + 1.0f) * 0.25f, 0.0f), 1.0f);
                        if (R > 0.0f)
                            sv = s[n][r] * SCL +
                                 ((R < 1.0f) ? __log2f(R + 1e-10f) : 0.0f);
                    }
                    s[n][r] = sv;
                    tmax = fmaxf(tmax, sv);
                }
            }
        }

        // ---- online softmax state: scalar per lane (q = nl), 2 shuffles ----
        float t2 = fmaxf(tmax, __shfl_xor(tmax, 16));
        t2 = fmaxf(t2, __shfl_xor(t2, 32));
        const float m_new = fmaxf(m_r, t2);
        const float alpha = exp2f(m_r - m_new);
        m_r = m_new;

        // ---- P = exp2(S - m) -> bf16 Ps via cvt_pk + ds_write_b64 ----
        float psum = 0.0f;
#pragma unroll
        for (int n = 0; n < 4; ++n) {
            u32 w0 = 0, w1 = 0;
            if (any[n]) {
                const float p0 = exp2f(s[n][0] - m_r);
                const float p1 = exp2f(s[n][1] - m_r);
                const float p2 = exp2f(s[n][2] - m_r);
                const float p3 = exp2f(s[n][3] - m_r);
                psum += (p0 + p1) + (p2 + p3);
                w0 = cvt_pk_bf16(p0, p1);
                w1 = cvt_pk_bf16(p2, p3);
            }
            uint2 wv; wv.x = w0; wv.y = w1;
            *(uint2*)&Psw[nl * 64 + ((n * 16 + quad * 4) ^ swz)] = wv;
        }
        float ps = psum + __shfl_xor(psum, 16);
        ps += __shfl_xor(ps, 32);
        l_r = l_r * alpha + ps;
#pragma unroll
        for (int d = 0; d < 4; ++d)
#pragma unroll
            for (int r = 0; r < 4; ++r) o[d][r] *= alpha;

        // ---- O += V^T P^T (swapped): A = V-frag (unchanged reads), B = P-frag
        const bool kf0 = any[0] | any[1];
        const bool kf1 = any[2] | any[3];
        short8 pa0 = *(const short8*)&Psw[nl * 64 + ((quad * 8) ^ swz)];
        short8 pa1 = *(const short8*)&Psw[nl * 64 + ((32 + quad * 8) ^ swz)];
        __builtin_amdgcn_s_setprio(1);
#pragma unroll
        for (int d = 0; d < 4; ++d) {
            const int vrow = d * 16 + nl;
            const u16* vp = Vs + vrow * 64;
            if (kf0) {
                short8 vb0 = *(const short8*)(vp + ((quad ^ (vrow & 7)) * 8));
                o[d] = __builtin_amdgcn_mfma_f32_16x16x32_bf16(vb0, pa0, o[d], 0, 0, 0);
            }
            if (kf1) {
                short8 vb1 = *(const short8*)(vp + (((4 + quad) ^ (vrow & 7)) * 8));
                o[d] = __builtin_amdgcn_mfma_f32_16x16x32_bf16(vb1, pa1, o[d], 0, 0, 0);
            }
        }
        __builtin_amdgcn_s_setprio(0);
    }

    // ---- epilogue: O[q=nl][dcol=d*16+quad*4+r]; scalar 1/l; 8B stores ----
    const float inv_l = 1.0f / l_r;
    u16* op = out + (size_t)(b * T_SEQ + q0 + nl) * DMODEL + h * 64 + quad * 4;
#pragma unroll
    for (int d = 0; d < 4; ++d) {
        uint2 wv;
        wv.x = cvt_pk_bf16(o[d][0] * inv_l, o[d][1] * inv_l);
        wv.y = cvt_pk_bf16(o[d][2] * inv_l, o[d][3] * inv_l);
        *(uint2*)(op + d * 16) = wv;
    }
}

extern "C" void kernel_launch(void* const* d_in, const int* in_sizes, int n_in,
                              void* d_out, int out_size, void* d_ws, size_t ws_size,
                              hipStream_t stream)
{
    (void)in_sizes; (void)n_in; (void)out_size; (void)ws_size;
    const float* x  = (const float*)d_in[0];
    const float* wq = (const float*)d_in[1];
    const float* wk = (const float*)d_in[2];
    const float* wv = (const float*)d_in[3];
    const float* wo = (const float*)d_in[4];
    const float* sp = (const float*)d_in[5];
    float* out = (float*)d_out;

    const size_t elems = (size_t)4 * T_SEQ * DMODEL;  // 4,194,304
    u16* xb  = (u16*)d_ws;
    u16* Qb  = xb  + elems;
    u16* Kb  = Qb  + elems;
    u16* Vb  = Kb  + elems;
    u16* Vtb = Vb  + elems;
    u16* Ab  = Vtb + elems;
    u16* wqb = Ab  + elems;
    u16* wkb = wqb + 262144;
    u16* wvb = wkb + 262144;
    u16* wob = wvb + 262144;

    // casts + loss (one launch)
    cast_all<<<5120, 256, 0, stream>>>(x, wq, wk, wv, wo, sp,
                                       xb, wqb, wkb, wvb, wob, out + elems);
    // Q,K,V projections
    gemm_bf16<<<dim3(64, 4, 3), 256, 0, stream>>>(
        xb, wqb, wkb, wvb, Qb, Kb, Vb, nullptr, 1);
    // V -> V^T per head
    transpose_v<<<dim3(32, 32), 256, 0, stream>>>(Vb, Vtb);
    // LDS-staged MFMA windowed flash attention, swapped-operand layout
    attn_mfma<<<dim3(2048), 128, 0, stream>>>(Qb, Kb, Vtb, sp, Ab);
    // output projection (fp32 out)
    gemm_bf16<<<dim3(64, 4, 1), 256, 0, stream>>>(
        Ab, wob, wob, wob, nullptr, nullptr, nullptr, out, 0);
}

// Round 8
// 149.831 us; speedup vs baseline: 1.1700x; 1.0176x over previous
//
#include <hip/hip_runtime.h>
#include <math.h>

#define T_SEQ   2048
#define DMODEL  512
#define NHEADS  8
#define DH      64
#define NEG_INF -1.0e9f

typedef __attribute__((ext_vector_type(8))) short short8;
typedef __attribute__((ext_vector_type(4))) float f32x4;
typedef unsigned int u32;
typedef unsigned short u16;

// cheap bf16 pack: round-half-up, error <= 2^-9 rel (same bound as RNE). No NaNs here.
__device__ __forceinline__ u16 f2bf(float f) {
    union { float f; u32 u; } w; w.f = f;
    return (u16)((w.u + 0x8000u) >> 16);
}

// packed f32x2 -> bf16x2 (RNE), single instruction on gfx950
__device__ __forceinline__ u32 cvt_pk_bf16(float lo, float hi) {
    u32 r;
    asm("v_cvt_pk_bf16_f32 %0, %1, %2" : "=v"(r) : "v"(lo), "v"(hi));
    return r;
}

// async global->LDS, 16B per lane. LDS dest must be wave-uniform base + lane*16.
__device__ __forceinline__ void async_load16(const u16* g, u16* l) {
    __builtin_amdgcn_global_load_lds(
        (const __attribute__((address_space(1))) u32*)(const void*)g,
        (__attribute__((address_space(3))) u32*)(void*)l, 16, 0, 0);
}

// ---------------------------------------------------------------------------
// fused fp32->bf16 casts (x + 4 weights) + span-loss scalar. 5120 blocks.
// ---------------------------------------------------------------------------
__global__ void cast_all(const float* __restrict__ x,  const float* __restrict__ wq,
                         const float* __restrict__ wk, const float* __restrict__ wv,
                         const float* __restrict__ wo, const float* __restrict__ sp,
                         u16* __restrict__ xb,  u16* __restrict__ wqb,
                         u16* __restrict__ wkb, u16* __restrict__ wvb,
                         u16* __restrict__ wob, float* __restrict__ loss_out)
{
    const int bid = blockIdx.x;
    const float* src; u16* dst; int i;
    if (bid < 4096) { src = x; dst = xb; i = bid * 256 + threadIdx.x; }
    else {
        const int wsel = (bid - 4096) >> 8;
        src = (wsel == 0) ? wq : (wsel == 1) ? wk : (wsel == 2) ? wv : wo;
        dst = (wsel == 0) ? wqb : (wsel == 1) ? wkb : (wsel == 2) ? wvb : wob;
        i = ((bid - 4096) & 255) * 256 + threadIdx.x;
    }
    float4 v = ((const float4*)src)[i];
    ushort4 o;
    o.x = f2bf(v.x); o.y = f2bf(v.y); o.z = f2bf(v.z); o.w = f2bf(v.w);
    ((ushort4*)dst)[i] = o;
    if (bid == 5119 && threadIdx.x == 0) {
        float s = 0.0f;
        for (int h = 0; h < NHEADS; ++h)
            s += fminf(fmaxf(sp[h], 0.0f), 1.0f);
        loss_out[0] = 2e-4f * (s * 0.125f);
    }
}

// ---------------------------------------------------------------------------
// bf16 MFMA GEMM: C[m][n] = sum_k A[m][k]*W[n][k]  (A @ W^T)
// scatter=1: bf16 -> (B,H,T,DH) via LDS-coalesced epilogue; 0: fp32 row-major.
// ---------------------------------------------------------------------------
__global__ __launch_bounds__(256)
void gemm_bf16(const u16* __restrict__ A,
               const u16* __restrict__ W0, const u16* __restrict__ W1,
               const u16* __restrict__ W2,
               u16* __restrict__ Cb0, u16* __restrict__ Cb1,
               u16* __restrict__ Cb2,
               float* __restrict__ Cf, int scatter)
{
    constexpr int K = 512, BK = 64;
    const u16* W  = (blockIdx.z == 0) ? W0 : (blockIdx.z == 1) ? W1 : W2;
    u16*       Cb = (blockIdx.z == 0) ? Cb0 : (blockIdx.z == 1) ? Cb1 : Cb2;

    __shared__ __align__(16) u16 smem[16384];   // 32 KB: As|Bs, reused by epilogue
    u16* As = smem;
    u16* Bs = smem + 8192;

    const int t    = threadIdx.x;
    const int lane = t & 63;
    const int wave = t >> 6;
    const int wm   = wave >> 1, wn = wave & 1;
    const int m0   = blockIdx.x * 128, n0 = blockIdx.y * 128;

    const int srow = t >> 3;
    const int kb   = (t & 7) ^ (srow & 7);
    const u16* gA = A + (size_t)(m0 + srow) * K + kb * 8;
    const u16* gW = W + (size_t)(n0 + srow) * K + kb * 8;

    const int rA = wm * 64 + (lane & 15);
    const int rB = wn * 64 + (lane & 15);
    const int kq = lane >> 4;
    const int offA0 = rA * BK + ((kq      ^ (rA & 7)) * 8);
    const int offA1 = rA * BK + (((4 + kq) ^ (rA & 7)) * 8);
    const int offB0 = rB * BK + ((kq      ^ (rB & 7)) * 8);
    const int offB1 = rB * BK + (((4 + kq) ^ (rB & 7)) * 8);

    f32x4 acc[4][4];
#pragma unroll
    for (int it = 0; it < 4; ++it)
#pragma unroll
        for (int jt = 0; jt < 4; ++jt) acc[it][jt] = (f32x4)0.0f;

    for (int k0 = 0; k0 < K; k0 += BK) {
        __syncthreads();
#pragma unroll
        for (int i = 0; i < 4; ++i) {
            async_load16(gA + k0 + i * (32 * K), As + t * 8 + i * 2048);
            async_load16(gW + k0 + i * (32 * K), Bs + t * 8 + i * 2048);
        }
        __syncthreads();

        short8 af[4][2], bfr[4][2];
#pragma unroll
        for (int it = 0; it < 4; ++it) {
            af[it][0]  = *(const short8*)(As + offA0 + it * 16 * BK);
            af[it][1]  = *(const short8*)(As + offA1 + it * 16 * BK);
            bfr[it][0] = *(const short8*)(Bs + offB0 + it * 16 * BK);
            bfr[it][1] = *(const short8*)(Bs + offB1 + it * 16 * BK);
        }
#pragma unroll
        for (int it = 0; it < 4; ++it)
#pragma unroll
            for (int jt = 0; jt < 4; ++jt) {
                acc[it][jt] = __builtin_amdgcn_mfma_f32_16x16x32_bf16(
                    af[it][0], bfr[jt][0], acc[it][jt], 0, 0, 0);
                acc[it][jt] = __builtin_amdgcn_mfma_f32_16x16x32_bf16(
                    af[it][1], bfr[jt][1], acc[it][jt], 0, 0, 0);
            }
    }

    const int r0 = (lane >> 4) * 4;
    const int cl = lane & 15;

    if (scatter) {
        // two rounds; each stages a 64-row x 128-col bf16 slice (pitch 136) in LDS,
        // then stores coalesced uint4 to (B,H,T,DH).
        constexpr int P = 136;
#pragma unroll
        for (int rnd = 0; rnd < 2; ++rnd) {
            __syncthreads();   // prior use of smem done
#pragma unroll
            for (int s = 0; s < 2; ++s) {
                const int it = rnd * 2 + s;
                const int lrow = wm * 32 + s * 16 + r0;
#pragma unroll
                for (int jt = 0; jt < 4; ++jt) {
                    const int cc = wn * 64 + jt * 16 + cl;
#pragma unroll
                    for (int r = 0; r < 4; ++r)
                        smem[(lrow + r) * P + cc] = f2bf(acc[it][jt][r]);
                }
            }
            __syncthreads();
            const int lrow2 = t >> 2;
            const int h2    = (t >> 1) & 1;
            const int dhalf = t & 1;
            const int grow  = m0 + (lrow2 >> 5) * 64 + rnd * 32 + (lrow2 & 31);
            const int b     = grow >> 11, tt = grow & 2047;
            const int h     = (n0 >> 6) + h2;
            u16* dst = Cb + ((size_t)((b * NHEADS + h) * T_SEQ + tt)) * DH + dhalf * 32;
            const u16* srcl = smem + lrow2 * P + h2 * 64 + dhalf * 32;
#pragma unroll
            for (int i = 0; i < 4; ++i)
                ((uint4*)dst)[i] = *(const uint4*)(srcl + i * 8);
        }
    } else {
#pragma unroll
        for (int it = 0; it < 4; ++it) {
#pragma unroll
            for (int r = 0; r < 4; ++r) {
                const int row = m0 + wm * 64 + it * 16 + r0 + r;
#pragma unroll
                for (int jt = 0; jt < 4; ++jt) {
                    const int col = n0 + wn * 64 + jt * 16 + cl;
                    Cf[(size_t)row * DMODEL + col] = acc[it][jt][r];
                }
            }
        }
    }
}

// ---------------------------------------------------------------------------
// V (B,H,T,DH) -> Vt (B,H,DH,T), bf16, 64x64 LDS tiles.
// ---------------------------------------------------------------------------
__global__ __launch_bounds__(256)
void transpose_v(const u16* __restrict__ V, u16* __restrict__ Vt)
{
    __shared__ u16 tile[64][72];
    const int bh = blockIdx.y;
    const int j0 = blockIdx.x * 64;
    const u16* src = V + (size_t)bh * (T_SEQ * DH) + (size_t)j0 * DH;
    u16* dst = Vt + (size_t)bh * (T_SEQ * DH) + j0;
    const int t = threadIdx.x;
    const int jr = t >> 2, c0 = (t & 3) * 16;
    uint4 a = *(const uint4*)(src + (size_t)jr * DH + c0);
    uint4 b = *(const uint4*)(src + (size_t)jr * DH + c0 + 8);
    *(uint4*)&tile[jr][c0]     = a;
    *(uint4*)&tile[jr][c0 + 8] = b;
    __syncthreads();
    const int d = t >> 2, jc = (t & 3) * 16;
    union { uint4 v; u16 s[8]; } pa, pb;
#pragma unroll
    for (int i = 0; i < 8; ++i) pa.s[i] = tile[jc + i][d];
#pragma unroll
    for (int i = 0; i < 8; ++i) pb.s[i] = tile[jc + 8 + i][d];
    *(uint4*)(dst + (size_t)d * T_SEQ + jc)     = pa.v;
    *(uint4*)(dst + (size_t)d * T_SEQ + jc + 8) = pb.v;
}

// ---------------------------------------------------------------------------
// MFMA windowed flash attention v8 = round-7 + qb-interleaved balance.
// Round-7 mapping fixed h per resident class but ALSO fixed qb -> per-CU
// work still varied ~5x with qb (qb=0 class: 8 tile-iters; qb=63: ~42) ->
// measured 27% time-avg occupancy = idle early-finishing CUs.
// v8: qb = ((c&63) + 8*k)&63 -> each stride-256 resident class covers all 8
// heads AND a stride-8 spread of qb -> per-CU work ~= (1/8) * total, uniform.
// Bijective: (h,b,qb) -> l = h*256 + (b<<6) + ((qb-8h)&63).
// Within a 256-block run h is constant and qb increments -> same-XCD
// neighbors still share overlapping K/V windows (L2 locality kept).
// Everything else identical to round 7 (best: 152.5 us total).
// Q,K in (B,H,T,DH); Vt in (B,H,DH,T); out bf16 (B,T,DMODEL).
// ---------------------------------------------------------------------------
__global__ __launch_bounds__(128)
void attn_mfma(const u16* __restrict__ Q, const u16* __restrict__ K,
               const u16* __restrict__ Vt, const float* __restrict__ span_params,
               u16* __restrict__ out)
{
    __shared__ __align__(16) u16 Ks[64 * 64];      // [j][dh], XOR-swizzled granules
    __shared__ __align__(16) u16 Vs[64 * 64];      // [dh][j], XOR-swizzled granules
    __shared__ __align__(16) u16 Ps[2][1024];      // per-wave P [q=16][j=64], row 128B

    const int tid  = threadIdx.x;
    const int lane = tid & 63;
    const int w    = tid >> 6;
    const int nl   = lane & 15;
    const int quad = lane >> 4;
    const int swz  = (nl & 7) << 3;                // u16-unit XOR (bytes: (nl&7)<<4)

    // balanced bijective mapping: head from high bits, qb rotated by head so
    // each stride-256 resident class spans all heads AND a stride-8 qb spread.
    const int l  = blockIdx.x;              // 0..2047
    const int k  = l >> 8;                  // 0..7
    const int c  = l & 255;
    const int h  = k;
    const int b  = c >> 6;
    const int qb = ((c & 63) + 8 * k) & 63;
    const int bh = b * 8 + h;
    const int i0 = qb * 32;
    const int q0 = i0 + w * 16;

    const u16* Qh = Q  + (size_t)bh * (T_SEQ * DH);
    const u16* Kh = K  + (size_t)bh * (T_SEQ * DH);
    const u16* Vh = Vt + (size_t)bh * (DH * T_SEQ);

    float span = span_params[h];
    span = fminf(fmaxf(span, 0.0f), 1.0f);
    const float eff_span = span * 512.0f;
    const int wspan = (int)(eff_span + 1.0f) + 1;

    const float SCL = 0.125f * 1.44269504f;  // (1/sqrt(64)) * log2(e)

    // Q fragments (used as MFMA B-operand; same per-lane layout as A)
    short8 qf0 = *(const short8*)(Qh + (size_t)(q0 + nl) * DH + quad * 8);
    short8 qf1 = *(const short8*)(Qh + (size_t)(q0 + nl) * DH + 32 + quad * 8);

    // staging: 128 threads, 16 rows per issue, 4 issues per buffer
    const int srow = tid >> 3;                     // 0..15
    const int sg   = (tid & 7) ^ (srow & 7);
    const u16* gK = Kh + (size_t)srow * DH + sg * 8;
    const u16* gV = Vh + (size_t)srow * T_SEQ + sg * 8;

    f32x4 o[4];                 // O[q=nl][dcol = d*16 + quad*4 + r]
    float m_r = -1.0e30f, l_r = 0.0f;
#pragma unroll
    for (int d = 0; d < 4; ++d) o[d] = (f32x4)0.0f;

    int j_lo = i0 - wspan;
    if (j_lo < 0) j_lo = 0;
    j_lo &= ~63;

    u16* Psw = Ps[w];

    for (int j0 = j_lo; j0 <= i0 + 31; j0 += 64) {
        __syncthreads();
#pragma unroll
        for (int i = 0; i < 4; ++i) {
            async_load16(gK + (size_t)(j0 + i * 16) * DH, Ks + tid * 8 + i * 1024);
            async_load16(gV + j0 + (size_t)(i * 16) * T_SEQ, Vs + tid * 8 + i * 1024);
        }
        __syncthreads();

        // ---- S^T = K Q^T per 16-wide key tile: lane holds S[q=nl][j=quad*4+r]
        f32x4 s[4];
        bool any[4];
        __builtin_amdgcn_s_setprio(1);
#pragma unroll
        for (int n = 0; n < 4; ++n) {
            const int jn = j0 + n * 16;
            any[n] = (jn <= q0 + 15) &&
                     ((float)(q0 - jn - 15) < eff_span + 1.0f);   // R>0 exists
            s[n] = (f32x4)0.0f;
            if (any[n]) {
                const int row = n * 16 + nl;
                const u16* kp = Ks + row * 64;
                short8 b0 = *(const short8*)(kp + ((quad ^ (row & 7)) * 8));
                short8 b1 = *(const short8*)(kp + (((4 + quad) ^ (row & 7)) * 8));
                s[n] = __builtin_amdgcn_mfma_f32_16x16x32_bf16(b0, qf0, s[n], 0, 0, 0);
                s[n] = __builtin_amdgcn_mfma_f32_16x16x32_bf16(b1, qf1, s[n], 0, 0, 0);
            }
        }
        __builtin_amdgcn_s_setprio(0);

        // ---- mask + row max (per-lane scalar), 3-way tile classification ----
        const int qg = q0 + nl;
        float tmax = -1.0e30f;
#pragma unroll
        for (int n = 0; n < 4; ++n) {
            if (!any[n]) continue;
            const int jn = j0 + n * 16;
            const int jb = jn + quad * 4;
            const bool causal_b = (jn + 15 > q0);                           // some dist<0
            const bool span_b   = ((float)(q0 + 15 - jn) > eff_span - 3.0f); // some R<1
            if (!causal_b && !span_b) {
#pragma unroll
                for (int r = 0; r < 4; ++r) {
                    const float sv = s[n][r] * SCL;
                    s[n][r] = sv;
                    tmax = fmaxf(tmax, sv);
                }
            } else if (!span_b) {
#pragma unroll
                for (int r = 0; r < 4; ++r) {
                    const int dist = qg - (jb + r);
                    const float sv = (dist >= 0) ? s[n][r] * SCL : NEG_INF;
                    s[n][r] = sv;
                    tmax = fmaxf(tmax, sv);
                }
            } else {
#pragma unroll
                for (int r = 0; r < 4; ++r) {
                    const int dist = qg - (jb + r);
                    float sv = NEG_INF;
                    if (dist >= 0) {
                        float xv = eff_span - (float)dist;
                        float R  = fminf(fmaxf((xv + 1.0f) * 0.25f, 0.0f), 1.0f);
                        if (R > 0.0f)
                            sv = s[n][r] * SCL +
                                 ((R < 1.0f) ? __log2f(R + 1e-10f) : 0.0f);
                    }
                    s[n][r] = sv;
                    tmax = fmaxf(tmax, sv);
                }
            }
        }

        // ---- online softmax state: scalar per lane (q = nl), 2 shuffles ----
        float t2 = fmaxf(tmax, __shfl_xor(tmax, 16));
        t2 = fmaxf(t2, __shfl_xor(t2, 32));
        const float m_new = fmaxf(m_r, t2);
        const float alpha = exp2f(m_r - m_new);
        m_r = m_new;

        // ---- P = exp2(S - m) -> bf16 Ps via cvt_pk + ds_write_b64 ----
        float psum = 0.0f;
#pragma unroll
        for (int n = 0; n < 4; ++n) {
            u32 w0 = 0, w1 = 0;
            if (any[n]) {
                const float p0 = exp2f(s[n][0] - m_r);
                const float p1 = exp2f(s[n][1] - m_r);
                const float p2 = exp2f(s[n][2] - m_r);
                const float p3 = exp2f(s[n][3] - m_r);
                psum += (p0 + p1) + (p2 + p3);
                w0 = cvt_pk_bf16(p0, p1);
                w1 = cvt_pk_bf16(p2, p3);
            }
            uint2 wv; wv.x = w0; wv.y = w1;
            *(uint2*)&Psw[nl * 64 + ((n * 16 + quad * 4) ^ swz)] = wv;
        }
        float ps = psum + __shfl_xor(psum, 16);
        ps += __shfl_xor(ps, 32);
        l_r = l_r * alpha + ps;
#pragma unroll
        for (int d = 0; d < 4; ++d)
#pragma unroll
            for (int r = 0; r < 4; ++r) o[d][r] *= alpha;

        // ---- O += V^T P^T (swapped): A = V-frag (unchanged reads), B = P-frag
        const bool kf0 = any[0] | any[1];
        const bool kf1 = any[2] | any[3];
        short8 pa0 = *(const short8*)&Psw[nl * 64 + ((quad * 8) ^ swz)];
        short8 pa1 = *(const short8*)&Psw[nl * 64 + ((32 + quad * 8) ^ swz)];
        __builtin_amdgcn_s_setprio(1);
#pragma unroll
        for (int d = 0; d < 4; ++d) {
            const int vrow = d * 16 + nl;
            const u16* vp = Vs + vrow * 64;
            if (kf0) {
                short8 vb0 = *(const short8*)(vp + ((quad ^ (vrow & 7)) * 8));
                o[d] = __builtin_amdgcn_mfma_f32_16x16x32_bf16(vb0, pa0, o[d], 0, 0, 0);
            }
            if (kf1) {
                short8 vb1 = *(const short8*)(vp + (((4 + quad) ^ (vrow & 7)) * 8));
                o[d] = __builtin_amdgcn_mfma_f32_16x16x32_bf16(vb1, pa1, o[d], 0, 0, 0);
            }
        }
        __builtin_amdgcn_s_setprio(0);
    }

    // ---- epilogue: O[q=nl][dcol=d*16+quad*4+r]; scalar 1/l; 8B stores ----
    const float inv_l = 1.0f / l_r;
    u16* op = out + (size_t)(b * T_SEQ + q0 + nl) * DMODEL + h * 64 + quad * 4;
#pragma unroll
    for (int d = 0; d < 4; ++d) {
        uint2 wv;
        wv.x = cvt_pk_bf16(o[d][0] * inv_l, o[d][1] * inv_l);
        wv.y = cvt_pk_bf16(o[d][2] * inv_l, o[d][3] * inv_l);
        *(uint2*)(op + d * 16) = wv;
    }
}

extern "C" void kernel_launch(void* const* d_in, const int* in_sizes, int n_in,
                              void* d_out, int out_size, void* d_ws, size_t ws_size,
                              hipStream_t stream)
{
    (void)in_sizes; (void)n_in; (void)out_size; (void)ws_size;
    const float* x  = (const float*)d_in[0];
    const float* wq = (const float*)d_in[1];
    const float* wk = (const float*)d_in[2];
    const float* wv = (const float*)d_in[3];
    const float* wo = (const float*)d_in[4];
    const float* sp = (const float*)d_in[5];
    float* out = (float*)d_out;

    const size_t elems = (size_t)4 * T_SEQ * DMODEL;  // 4,194,304
    u16* xb  = (u16*)d_ws;
    u16* Qb  = xb  + elems;
    u16* Kb  = Qb  + elems;
    u16* Vb  = Kb  + elems;
    u16* Vtb = Vb  + elems;
    u16* Ab  = Vtb + elems;
    u16* wqb = Ab  + elems;
    u16* wkb = wqb + 262144;
    u16* wvb = wkb + 262144;
    u16* wob = wvb + 262144;

    // casts + loss (one launch)
    cast_all<<<5120, 256, 0, stream>>>(x, wq, wk, wv, wo, sp,
                                       xb, wqb, wkb, wvb, wob, out + elems);
    // Q,K,V projections
    gemm_bf16<<<dim3(64, 4, 3), 256, 0, stream>>>(
        xb, wqb, wkb, wvb, Qb, Kb, Vb, nullptr, 1);
    // V -> V^T per head
    transpose_v<<<dim3(32, 32), 256, 0, stream>>>(Vb, Vtb);
    // LDS-staged MFMA windowed flash attention, h+qb interleaved balance
    attn_mfma<<<dim3(2048), 128, 0, stream>>>(Qb, Kb, Vtb, sp, Ab);
    // output projection (fp32 out)
    gemm_bf16<<<dim3(64, 4, 1), 256, 0, stream>>>(
        Ab, wob, wob, wob, nullptr, nullptr, nullptr, out, 0);
}